// Round 3
// baseline (9044.784 us; speedup 1.0000x reference)
//
#include <hip/hip_runtime.h>
#include <hip/hip_bf16.h>

// FCN hypernetwork, batch-chunked: per-sample generated conv weights, BN folded
// into consumer loads (scale/shift per (b,c) from raw-output sum/sumsq
// accumulated by producer conv epilogues via atomics). BN stats are per-sample,
// so the batch is chunked through small ping-pong buffers; chunk size C adapts
// to ws_size (C=8 -> ~93 MB; never assumes a large workspace).
//
// Workspace layout (floats):
//   wg : 32*202112 = 6,467,584       generated weights, all samples (26 MB)
//   st : 14,848                      stats [layer][b][c][{sum,sumsq}] (full batch)
//   A  : C*1,048,576                 ping buffer (chunk activations)
//   B  : C*1,048,576                 pong buffer

#define NB 32
#define WG_STRIDE 202112

__device__ __forceinline__ float wave_reduce2(float& s, float& q) {
    #pragma unroll
    for (int o = 32; o > 0; o >>= 1) {
        s += __shfl_down(s, o, 64);
        q += __shfl_down(q, o, 64);
    }
    return s;
}

// ---------------- weight generation: y = W @ a + b for all samples ----------
__global__ __launch_bounds__(256) void wgen_kernel(
    const float* __restrict__ act,
    const float* __restrict__ W1, const float* __restrict__ b1,
    const float* __restrict__ W2, const float* __restrict__ b2,
    const float* __restrict__ W3, const float* __restrict__ b3,
    const float* __restrict__ W4, const float* __restrict__ b4,
    const float* __restrict__ W5, const float* __restrict__ b5,
    const float* __restrict__ W6, const float* __restrict__ b6,
    const float* __restrict__ W7, const float* __restrict__ b7,
    float* __restrict__ wg)
{
    __shared__ float s_a[NB * 32];
    int tid = threadIdx.x;
    for (int i = tid; i < NB * 32; i += 256) s_a[i] = act[i];
    __syncthreads();

    int j = blockIdx.x * 256 + tid;
    if (j >= WG_STRIDE) return;

    const float* W; const float* bb; int off;
    if      (j <   3200) { W = W1; bb = b1; off = 0; }
    else if (j <   9600) { W = W2; bb = b2; off = 3200; }
    else if (j <  22400) { W = W3; bb = b3; off = 9600; }
    else if (j <  48000) { W = W4; bb = b4; off = 22400; }
    else if (j <  99200) { W = W5; bb = b5; off = 48000; }
    else if (j < 201600) { W = W6; bb = b6; off = 99200; }
    else                 { W = W7; bb = b7; off = 201600; }
    int jl = j - off;

    float4 wr[8];
    const float4* Wr = (const float4*)(W + (size_t)jl * 32);
    #pragma unroll
    for (int k = 0; k < 8; k++) wr[k] = Wr[k];
    float bias = bb[jl];

    for (int b = 0; b < NB; b++) {
        const float* a = &s_a[b * 32];
        float s = bias;
        #pragma unroll
        for (int k = 0; k < 8; k++) {
            s += wr[k].x * a[4*k+0] + wr[k].y * a[4*k+1]
               + wr[k].z * a[4*k+2] + wr[k].w * a[4*k+3];
        }
        wg[(size_t)b * WG_STRIDE + j] = s;
    }
}

// ---------------- stats over x (one block per (b,c)), full batch ------------
__global__ __launch_bounds__(256) void stats_x_kernel(
    const float* __restrict__ x, float* __restrict__ st)
{
    __shared__ float s_red[4][2];
    int bc = blockIdx.x;               // b*8 + c
    const float* p = x + (size_t)bc * 65536;
    float s = 0.f, q = 0.f;
    for (int i = threadIdx.x; i < 65536; i += 256) {
        float v = p[i];
        s += v; q += v * v;
    }
    wave_reduce2(s, q);
    int lane = threadIdx.x & 63, wid = threadIdx.x >> 6;
    if (lane == 0) { s_red[wid][0] = s; s_red[wid][1] = q; }
    __syncthreads();
    if (threadIdx.x == 0) {
        float ts = 0, tq = 0;
        #pragma unroll
        for (int w = 0; w < 4; w++) { ts += s_red[w][0]; tq += s_red[w][1]; }
        st[bc * 2 + 0] = ts;
        st[bc * 2 + 1] = tq;
    }
}

// ---------------- 5x5 conv, dilation DIL, pad 2*DIL, BN-on-load -------------
// Block: 256 threads, 32x32 output tile, 4 out-channels. blockIdx.z = local
// sample within chunk; global sample b = b0 + bl (for wg/stats); activation
// buffers are chunk-local (indexed by bl).
template<int DIL, bool RELU>
__global__ __launch_bounds__(256) void conv5x5_kernel(
    const float* __restrict__ in, float* __restrict__ out,
    const float* __restrict__ wg, int wg_off, int b0,
    const float* __restrict__ stIn, float* __restrict__ stOut,
    const float* __restrict__ g, const float* __restrict__ be,
    int HW, int IC, int OC, float invN)
{
    constexpr int TIN = 32 + 4 * DIL;        // 36 (d1) / 40 (d2)
    constexpr int TT  = TIN * TIN;           // 1296 / 1600
    __shared__ __align__(16) float s_in[4 * TT];
    __shared__ __align__(16) float s_w[4][4][5][8];
    __shared__ float s_scale[64], s_shift[64];
    __shared__ float s_red[4][4][2];

    int tid = threadIdx.x;
    int bl  = blockIdx.z;              // chunk-local sample
    int b   = b0 + bl;                 // global sample
    int oc0 = blockIdx.y * 4;
    int tiles = HW >> 5;
    int ty0 = (blockIdx.x / tiles) << 5;
    int tx0 = (blockIdx.x % tiles) << 5;

    if (tid < IC) {
        float sum = stIn[(b * IC + tid) * 2 + 0];
        float sq  = stIn[(b * IC + tid) * 2 + 1];
        float m = sum * invN;
        float v = fmaxf(sq * invN - m * m, 0.f);
        float sc = g[tid] * rsqrtf(v + 1e-5f);
        s_scale[tid] = sc;
        s_shift[tid] = be[tid] - m * sc;
    }

    float acc[4][4] = {};
    const float* wgb = wg + (size_t)b * WG_STRIDE + wg_off;
    int ty  = tid >> 3;
    int tx4 = (tid & 7) * 4;

    for (int ic0 = 0; ic0 < IC; ic0 += 4) {
        __syncthreads();
        // stage weights: 4 oc x 4 ic x 25 taps, padded rows of 8
        for (int i = tid; i < 400; i += 256) {
            int oc = i / 100, r = i % 100;
            int ic = r / 25, t = r % 25;
            s_w[oc][ic][t / 5][t % 5] =
                wgb[(((size_t)(oc0 + oc)) * IC + ic0 + ic) * 25 + t];
        }
        // stage input tile with halo, BN(+relu) applied, zero OOB
        for (int i = tid; i < 4 * TT; i += 256) {
            int ic = i / TT, p = i % TT;
            int r = p / TIN, c = p % TIN;
            int gy = ty0 - 2 * DIL + r;
            int gx = tx0 - 2 * DIL + c;
            float v = 0.f;
            if (gy >= 0 && gy < HW && gx >= 0 && gx < HW) {
                float t = in[(((size_t)bl * IC + ic0 + ic) * HW + gy) * HW + gx];
                t = t * s_scale[ic0 + ic] + s_shift[ic0 + ic];
                if (RELU) t = fmaxf(t, 0.f);
                v = t;
            }
            s_in[i] = v;
        }
        __syncthreads();

        #pragma unroll
        for (int ic = 0; ic < 4; ic++) {
            #pragma unroll
            for (int ky = 0; ky < 5; ky++) {
                const float* rowp = &s_in[ic * TT + (ty + ky * DIL) * TIN + tx4];
                float seg[(DIL == 1) ? 8 : 12];
                #pragma unroll
                for (int s4 = 0; s4 < ((DIL == 1) ? 2 : 3); s4++)
                    *(float4*)&seg[s4 * 4] = *(const float4*)&rowp[s4 * 4];
                #pragma unroll
                for (int oc = 0; oc < 4; oc++) {
                    float4 wa = *(const float4*)&s_w[oc][ic][ky][0];
                    float  w4 = s_w[oc][ic][ky][4];
                    #pragma unroll
                    for (int kx = 0; kx < 5; kx++) {
                        float w = (kx == 0) ? wa.x : (kx == 1) ? wa.y :
                                  (kx == 2) ? wa.z : (kx == 3) ? wa.w : w4;
                        #pragma unroll
                        for (int px = 0; px < 4; px++)
                            acc[oc][px] += w * seg[px + kx * DIL];
                    }
                }
            }
        }
    }

    // write raw outputs (chunk-local buffer)
    #pragma unroll
    for (int oc = 0; oc < 4; oc++) {
        float4 o4 = make_float4(acc[oc][0], acc[oc][1], acc[oc][2], acc[oc][3]);
        *(float4*)&out[(((size_t)bl * OC + oc0 + oc) * HW + ty0 + ty) * HW + tx0 + tx4] = o4;
    }

    // accumulate raw stats for this layer's BN (consumer divides)
    int lane = tid & 63, wid = tid >> 6;
    #pragma unroll
    for (int oc = 0; oc < 4; oc++) {
        float s = acc[oc][0] + acc[oc][1] + acc[oc][2] + acc[oc][3];
        float q = acc[oc][0]*acc[oc][0] + acc[oc][1]*acc[oc][1]
                + acc[oc][2]*acc[oc][2] + acc[oc][3]*acc[oc][3];
        wave_reduce2(s, q);
        if (lane == 0) { s_red[wid][oc][0] = s; s_red[wid][oc][1] = q; }
    }
    __syncthreads();
    if (tid < 8) {
        int oc = tid >> 1, k = tid & 1;
        float v = s_red[0][oc][k] + s_red[1][oc][k] + s_red[2][oc][k] + s_red[3][oc][k];
        atomicAdd(&stOut[((size_t)b * OC + oc0 + oc) * 2 + k], v);
    }
}

// ---------------- 2x2 avg pool on raw activations (chunk-local) -------------
__global__ __launch_bounds__(256) void pool2_kernel(
    const float* __restrict__ in, float* __restrict__ out)
{
    int idx = blockIdx.x * 256 + threadIdx.x;   // C*16*128*128 threads
    int x  = idx & 127;
    int y  = (idx >> 7) & 127;
    int bc = idx >> 14;                         // local (bl*16 + c)
    const float* p = in + (size_t)bc * 65536 + (size_t)y * 2 * 256 + x * 2;
    out[idx] = 0.25f * (p[0] + p[1] + p[256] + p[257]);
}

// ---------------- 1x1 conv (layer 7), BN-on-load ----------------------------
__global__ __launch_bounds__(256) void conv1x1_kernel(
    const float* __restrict__ in, float* __restrict__ out,
    const float* __restrict__ wg, int b0,
    const float* __restrict__ stIn,
    const float* __restrict__ g, const float* __restrict__ be, float invN)
{
    __shared__ float s_w[512];
    __shared__ float s_scale[64], s_shift[64];
    int tid = threadIdx.x;
    int bl = blockIdx.y;
    int b  = b0 + bl;
    const float* wgb = wg + (size_t)b * WG_STRIDE + 201600;
    for (int i = tid; i < 512; i += 256) s_w[i] = wgb[i];
    if (tid < 64) {
        float sum = stIn[(b * 64 + tid) * 2 + 0];
        float sq  = stIn[(b * 64 + tid) * 2 + 1];
        float m = sum * invN;
        float v = fmaxf(sq * invN - m * m, 0.f);
        float sc = g[tid] * rsqrtf(v + 1e-5f);
        s_scale[tid] = sc;
        s_shift[tid] = be[tid] - m * sc;
    }
    __syncthreads();

    int p = blockIdx.x * 256 + tid;   // 0..16383
    const float* ip = in + (size_t)bl * 64 * 16384 + p;
    float acc[8] = {};
    for (int ic = 0; ic < 64; ic++) {
        float v = ip[(size_t)ic * 16384] * s_scale[ic] + s_shift[ic];
        #pragma unroll
        for (int o = 0; o < 8; o++) acc[o] += s_w[o * 64 + ic] * v;
    }
    float* op = out + (size_t)bl * 8 * 16384 + p;
    #pragma unroll
    for (int o = 0; o < 8; o++) op[(size_t)o * 16384] = acc[o];
}

// ---------------- bilinear up x2 (align_corners) + softmax ------------------
__global__ __launch_bounds__(256) void upsoft_kernel(
    const float* __restrict__ z7, float* __restrict__ outp, int b0)
{
    int idx = blockIdx.x * 256 + threadIdx.x;   // bl*65536 + y*256 + x
    int bl = idx >> 16;
    int b  = b0 + bl;
    int y = (idx >> 8) & 255;
    int x = idx & 255;
    const float kf = 127.f / 255.f;
    float sy = y * kf; int y0 = (int)sy; float wy = sy - y0; int y1 = min(y0 + 1, 127);
    float sx = x * kf; int x0 = (int)sx; float wx = sx - x0; int x1 = min(x0 + 1, 127);

    const float* base = z7 + (size_t)bl * 8 * 16384;
    float l[8];
    float mx = -1e30f;
    #pragma unroll
    for (int c = 0; c < 8; c++) {
        const float* pc = base + c * 16384;
        float v00 = pc[y0 * 128 + x0], v01 = pc[y0 * 128 + x1];
        float v10 = pc[y1 * 128 + x0], v11 = pc[y1 * 128 + x1];
        float a  = v00 * (1.f - wy) + v10 * wy;
        float bb = v01 * (1.f - wy) + v11 * wy;
        float v  = a * (1.f - wx) + bb * wx;
        l[c] = v;
        mx = fmaxf(mx, v);
    }
    float s = 0.f;
    #pragma unroll
    for (int c = 0; c < 8; c++) { l[c] = expf(l[c] - mx); s += l[c]; }
    float inv = 1.f / s;
    #pragma unroll
    for (int c = 0; c < 8; c++)
        outp[((size_t)b * 8 + c) * 65536 + y * 256 + x] = l[c] * inv;
}

// ---------------------------------------------------------------------------
extern "C" void kernel_launch(void* const* d_in, const int* in_sizes, int n_in,
                              void* d_out, int out_size, void* d_ws, size_t ws_size,
                              hipStream_t stream)
{
    const float* x   = (const float*)d_in[0];
    const float* act = (const float*)d_in[1];
    const float* W[7]; const float* bv[7];
    for (int i = 0; i < 7; i++) { W[i] = (const float*)d_in[2 + 2*i]; bv[i] = (const float*)d_in[3 + 2*i]; }
    const float* g[7]; const float* be[7];
    for (int i = 0; i < 7; i++) { g[i] = (const float*)d_in[16 + 2*i]; be[i] = (const float*)d_in[17 + 2*i]; }
    float* out = (float*)d_out;

    // Pick largest chunk C (samples) fitting ws_size. Deterministic per harness
    // (ws_size fixed), so every call does identical work. Cap at 8 (~93 MB) to
    // stay far from any plausible workspace limit.
    int C = 8;
    while (C > 1) {
        size_t need = (6467584ull + 14848ull + 2ull * (size_t)C * 1048576ull) * 4ull;
        if (need <= ws_size) break;
        C >>= 1;
    }

    float* ws = (float*)d_ws;
    float* wg = ws;                                  // 6,467,584 floats
    float* st = wg + 6467584;                        // 14,848 floats
    float* A  = st + 14848;                          // C*1,048,576 floats
    float* Bb = A + (size_t)C * 1048576;             // C*1,048,576 floats

    // stats accumulator sub-offsets (floats): [b][c][2] per layer, full batch
    float* stx = st + 0;       // x  : 8 ch
    float* st1 = st + 512;     // z1 : 16
    float* st2 = st + 1536;    // z2 : 16
    float* st3 = st + 2560;    // z3 : 32
    float* st4 = st + 4608;    // z4 : 32
    float* st5 = st + 6656;    // z5 : 64
    float* st6 = st + 10752;   // z6 : 64   (end 14848)

    hipMemsetAsync(st, 0, 14848 * sizeof(float), stream);

    wgen_kernel<<<790, 256, 0, stream>>>(act,
        W[0], bv[0], W[1], bv[1], W[2], bv[2], W[3], bv[3],
        W[4], bv[4], W[5], bv[5], W[6], bv[6], wg);

    stats_x_kernel<<<256, 256, 0, stream>>>(x, stx);

    const float iN256 = 1.f / 65536.f, iN128 = 1.f / 16384.f;

    for (int b0 = 0; b0 < NB; b0 += C) {
        const float* xc = x + (size_t)b0 * 8 * 65536;
        // conv1: x(8)@256 -> z1(16)@256 in A, dil2, BN0 on load
        conv5x5_kernel<2, false><<<dim3(64, 4, C), 256, 0, stream>>>(
            xc, A, wg, 0, b0, stx, st1, g[0], be[0], 256, 8, 16, iN256);
        // conv2: z1(16)@256 -> z2(16)@256 in B, dil1, BN1+relu on load
        conv5x5_kernel<1, true><<<dim3(64, 4, C), 256, 0, stream>>>(
            A, Bb, wg, 3200, b0, st1, st2, g[1], be[1], 256, 16, 16, iN256);
        // pool raw z2 -> p2@128 in A (affine commutes with avg-pool)
        pool2_kernel<<<C * 1024, 256, 0, stream>>>(Bb, A);
        // conv3: p2(16)@128 -> z3(32)@128 in B, dil2, BN2 on load (stats over 256^2)
        conv5x5_kernel<2, false><<<dim3(16, 8, C), 256, 0, stream>>>(
            A, Bb, wg, 9600, b0, st2, st3, g[2], be[2], 128, 16, 32, iN256);
        // conv4: z3(32) -> z4(32) in A, dil1, BN3+relu
        conv5x5_kernel<1, true><<<dim3(16, 8, C), 256, 0, stream>>>(
            Bb, A, wg, 22400, b0, st3, st4, g[3], be[3], 128, 32, 32, iN128);
        // conv5: z4(32) -> z5(64) in B, dil2, BN4
        conv5x5_kernel<2, false><<<dim3(16, 16, C), 256, 0, stream>>>(
            A, Bb, wg, 48000, b0, st4, st5, g[4], be[4], 128, 32, 64, iN128);
        // conv6: z5(64) -> z6(64) in A, dil1, BN5+relu
        conv5x5_kernel<1, true><<<dim3(16, 16, C), 256, 0, stream>>>(
            Bb, A, wg, 99200, b0, st5, st6, g[5], be[5], 128, 64, 64, iN128);
        // conv7: z6(64) -> z7(8) in B, 1x1, BN6 on load
        conv1x1_kernel<<<dim3(64, C), 256, 0, stream>>>(
            A, Bb, wg, b0, st6, g[6], be[6], iN128);
        // bilinear x2 + softmax -> out (global)
        upsoft_kernel<<<C * 256, 256, 0, stream>>>(Bb, out, b0);
    }
}

// Round 7
// 2149.431 us; speedup vs baseline: 4.2080x; 4.2080x over previous
//
#include <hip/hip_runtime.h>
#include <hip/hip_bf16.h>

// FCN hypernetwork, MFMA version with emulated-fp32 (bf16 hi/lo split).
// Pipeline per batch-chunk of C samples:
//   prepass (BN affine [+relu] [+pool] + hi/lo bf16 split + transpose to
//            [bl][plane][chunk][y][x][16ic])
//   -> convmf (implicit-GEMM 5x5 conv via mfma_f32_16x16x32_bf16, K=32 = 2 taps x 16ic;
//              3x virtual ic-chunks realize a_hi*w_hi + a_lo*w_hi + a_hi*w_lo;
//              raw fp32 out [y][x][oc] + per-channel sum/sumsq stats via atomics)
//   -> ... -> conv1x1 (fp32) -> upsample+softmax.
// Weights generated per sample (wgen) fp32 at stride WGF_STRIDE, then split to
// bf16 hi/lo planes [plane][tap26][oc][icp16] (wgt, stride WGT_STRIDE shorts).

#define NB 32
#define WGF_STRIDE 202112         // floats per sample in wg (fp32)
#define WGT_PLANE 212992          // shorts per plane per sample
#define WGT_STRIDE 425984         // shorts per sample (hi+lo)

typedef short short8 __attribute__((ext_vector_type(8)));
typedef float f32x4 __attribute__((ext_vector_type(4)));

__device__ __forceinline__ void f2bf2(float v, short& hi, short& lo) {
    __hip_bfloat16 h = __float2bfloat16(v);
    hi = *reinterpret_cast<short*>(&h);
    float r = v - __bfloat162float(h);
    __hip_bfloat16 l = __float2bfloat16(r);
    lo = *reinterpret_cast<short*>(&l);
}

__device__ __forceinline__ float wave_reduce2(float& s, float& q) {
    #pragma unroll
    for (int o = 32; o > 0; o >>= 1) {
        s += __shfl_down(s, o, 64);
        q += __shfl_down(q, o, 64);
    }
    return s;
}

// ---------------- weight generation: y = W @ a + b for all samples ----------
__global__ __launch_bounds__(256) void wgen_kernel(
    const float* __restrict__ act,
    const float* __restrict__ W1, const float* __restrict__ b1,
    const float* __restrict__ W2, const float* __restrict__ b2,
    const float* __restrict__ W3, const float* __restrict__ b3,
    const float* __restrict__ W4, const float* __restrict__ b4,
    const float* __restrict__ W5, const float* __restrict__ b5,
    const float* __restrict__ W6, const float* __restrict__ b6,
    const float* __restrict__ W7, const float* __restrict__ b7,
    float* __restrict__ wg)
{
    __shared__ float s_a[NB * 32];
    int tid = threadIdx.x;
    for (int i = tid; i < NB * 32; i += 256) s_a[i] = act[i];
    __syncthreads();

    int j = blockIdx.x * 256 + tid;
    if (j >= WGF_STRIDE) return;

    const float* W; const float* bb; int off;
    if      (j <   3200) { W = W1; bb = b1; off = 0; }
    else if (j <   9600) { W = W2; bb = b2; off = 3200; }
    else if (j <  22400) { W = W3; bb = b3; off = 9600; }
    else if (j <  48000) { W = W4; bb = b4; off = 22400; }
    else if (j <  99200) { W = W5; bb = b5; off = 48000; }
    else if (j < 201600) { W = W6; bb = b6; off = 99200; }
    else                 { W = W7; bb = b7; off = 201600; }
    int jl = j - off;

    float4 wr[8];
    const float4* Wr = (const float4*)(W + (size_t)jl * 32);
    #pragma unroll
    for (int k = 0; k < 8; k++) wr[k] = Wr[k];
    float bias = bb[jl];

    for (int b = 0; b < NB; b++) {
        const float* a = &s_a[b * 32];
        float s = bias;
        #pragma unroll
        for (int k = 0; k < 8; k++) {
            s += wr[k].x * a[4*k+0] + wr[k].y * a[4*k+1]
               + wr[k].z * a[4*k+2] + wr[k].w * a[4*k+3];
        }
        wg[(size_t)b * WGF_STRIDE + j] = s;
    }
}

// ---------------- split generated weights to bf16 hi/lo [pl][tap26][oc][icp]
__global__ __launch_bounds__(256) void wgt_kernel(
    const float* __restrict__ wg, short* __restrict__ wgt)
{
    long idx = (long)blockIdx.x * 256 + threadIdx.x;
    if (idx >= (long)NB * WGT_PLANE) return;
    int b = (int)(idx / WGT_PLANE);
    int r = (int)(idx - (long)b * WGT_PLANE);
    int base, icpl, ocl, icr, off;
    if      (r <   6656) { base = 0;      icpl = 4; ocl = 4; icr = 8;  off = 0; }
    else if (r <  13312) { base = 6656;   icpl = 4; ocl = 4; icr = 16; off = 3200; }
    else if (r <  26624) { base = 13312;  icpl = 4; ocl = 5; icr = 16; off = 9600; }
    else if (r <  53248) { base = 26624;  icpl = 5; ocl = 5; icr = 32; off = 22400; }
    else if (r < 106496) { base = 53248;  icpl = 5; ocl = 6; icr = 32; off = 48000; }
    else                 { base = 106496; icpl = 6; ocl = 6; icr = 64; off = 99200; }
    int rr  = r - base;
    int icp = rr & ((1 << icpl) - 1);
    int oc  = (rr >> icpl) & ((1 << ocl) - 1);
    int tap = rr >> (icpl + ocl);
    float v = 0.f;
    if (tap < 25 && icp < icr)
        v = wg[(size_t)b * WGF_STRIDE + off + (oc * icr + icp) * 25 + tap];
    short hi, lo;
    f2bf2(v, hi, lo);
    wgt[(size_t)b * WGT_STRIDE + r]             = hi;
    wgt[(size_t)b * WGT_STRIDE + WGT_PLANE + r] = lo;
}

// ---------------- stats over x (one block per (b,c)), full batch ------------
__global__ __launch_bounds__(256) void stats_x_kernel(
    const float* __restrict__ x, float* __restrict__ st)
{
    __shared__ float s_red[4][2];
    int bc = blockIdx.x;               // b*8 + c
    const float* p = x + (size_t)bc * 65536;
    float s = 0.f, q = 0.f;
    for (int i = threadIdx.x; i < 65536; i += 256) {
        float v = p[i];
        s += v; q += v * v;
    }
    wave_reduce2(s, q);
    int lane = threadIdx.x & 63, wid = threadIdx.x >> 6;
    if (lane == 0) { s_red[wid][0] = s; s_red[wid][1] = q; }
    __syncthreads();
    if (threadIdx.x == 0) {
        float ts = 0, tq = 0;
        #pragma unroll
        for (int w = 0; w < 4; w++) { ts += s_red[w][0]; tq += s_red[w][1]; }
        st[bc * 2 + 0] = ts;
        st[bc * 2 + 1] = tq;
    }
}

// ---------------- prepass for x: BN0 + hi/lo + [pl][y][x][16] (ic 8..15=0) --
__global__ __launch_bounds__(256) void prepass_x_kernel(
    const float* __restrict__ x, short* __restrict__ D,
    const float* __restrict__ stIn, const float* __restrict__ g,
    const float* __restrict__ be, int b0)
{
    int idx = blockIdx.x * 256 + threadIdx.x;  // bl*65536 + pix
    int pix = idx & 65535;
    int bl  = idx >> 16;
    int b   = b0 + bl;
    const float invN = 1.f / 65536.f;
    short ohi[16], olo[16];
    #pragma unroll
    for (int c = 0; c < 8; c++) {
        float sum = stIn[(b * 8 + c) * 2 + 0];
        float sq  = stIn[(b * 8 + c) * 2 + 1];
        float m = sum * invN;
        float vv = fmaxf(sq * invN - m * m, 0.f);
        float sc = g[c] * rsqrtf(vv + 1e-5f);
        float sh = be[c] - m * sc;
        float v = x[((size_t)b * 8 + c) * 65536 + pix];
        f2bf2(v * sc + sh, ohi[c], olo[c]);
    }
    #pragma unroll
    for (int c = 8; c < 16; c++) { ohi[c] = 0; olo[c] = 0; }
    short* dh = D + ((size_t)(bl * 2 + 0) * 65536 + pix) * 16;
    short* dl = D + ((size_t)(bl * 2 + 1) * 65536 + pix) * 16;
    *(int4*)(dh)     = *(int4*)&ohi[0];
    *(int4*)(dh + 8) = *(int4*)&ohi[8];
    *(int4*)(dl)     = *(int4*)&olo[0];
    *(int4*)(dl + 8) = *(int4*)&olo[8];
}

// ---------------- standard prepass: BN affine (+relu) + hi/lo + transpose ---
// in : raw z [bl][y][x][ICz] fp32; out: [bl][plane][chunk][y][x][16] bf16
template<int HWL2, int ICz, bool RELU>
__global__ __launch_bounds__(256) void prepass_kernel(
    const float* __restrict__ z, short* __restrict__ D,
    const float* __restrict__ stIn, const float* __restrict__ g,
    const float* __restrict__ be, float invN, int b0)
{
    constexpr int PIX = 1 << (2 * HWL2);
    constexpr int ICC = ICz / 16;
    int idx = blockIdx.x * 256 + threadIdx.x;   // bl*(PIX*ICz/4) + pix*(ICz/4) + c4i
    int c4  = (idx & (ICz / 4 - 1)) * 4;
    int pix = (idx >> (31 - __builtin_clz(ICz / 4))) & (PIX - 1);
    int bl  = idx >> (2 * HWL2 + (31 - __builtin_clz(ICz / 4)));
    int b   = b0 + bl;

    float4 v = *(const float4*)(z + ((size_t)bl * PIX + pix) * ICz + c4);
    short ohi[4], olo[4];
    #pragma unroll
    for (int j = 0; j < 4; j++) {
        int c = c4 + j;
        float sum = stIn[(b * ICz + c) * 2 + 0];
        float sq  = stIn[(b * ICz + c) * 2 + 1];
        float m = sum * invN;
        float vv = fmaxf(sq * invN - m * m, 0.f);
        float sc = g[c] * rsqrtf(vv + 1e-5f);
        float sh = be[c] - m * sc;
        float t = ((const float*)&v)[j] * sc + sh;
        if (RELU) t = fmaxf(t, 0.f);
        f2bf2(t, ohi[j], olo[j]);
    }
    int chunk = c4 >> 4, within = c4 & 15;
    short* dh = D + (((size_t)(bl * 2 + 0) * ICC + chunk) * PIX + pix) * 16 + within;
    short* dl = D + (((size_t)(bl * 2 + 1) * ICC + chunk) * PIX + pix) * 16 + within;
    *(int2*)dh = *(int2*)&ohi[0];
    *(int2*)dl = *(int2*)&olo[0];
}

// ---------------- pool prepass: BN2 affine + 2x2 avg + hi/lo ----------------
// in: z2 raw [bl][256][256][16] fp32 -> out D [bl][plane][128][128][16]
__global__ __launch_bounds__(256) void prepass_pool_kernel(
    const float* __restrict__ z, short* __restrict__ D,
    const float* __restrict__ stIn, const float* __restrict__ g,
    const float* __restrict__ be, int b0)
{
    int idx = blockIdx.x * 256 + threadIdx.x;  // bl*(16384*4) + pix*4 + c4i
    int c4  = (idx & 3) * 4;
    int pix = (idx >> 2) & 16383;
    int bl  = idx >> 16;
    int b   = b0 + bl;
    int y = pix >> 7, x = pix & 127;
    const float invN = 1.f / 65536.f;

    const float* p0 = z + (((size_t)bl * 65536 + (2 * y) * 256 + 2 * x) * 16) + c4;
    float4 v00 = *(const float4*)(p0);
    float4 v01 = *(const float4*)(p0 + 16);
    float4 v10 = *(const float4*)(p0 + 256 * 16);
    float4 v11 = *(const float4*)(p0 + 257 * 16);
    short ohi[4], olo[4];
    #pragma unroll
    for (int j = 0; j < 4; j++) {
        int c = c4 + j;
        float sum = stIn[(b * 16 + c) * 2 + 0];
        float sq  = stIn[(b * 16 + c) * 2 + 1];
        float m = sum * invN;
        float vv = fmaxf(sq * invN - m * m, 0.f);
        float sc = g[c] * rsqrtf(vv + 1e-5f);
        float sh = be[c] - m * sc;
        float a = 0.25f * (((const float*)&v00)[j] + ((const float*)&v01)[j]
                         + ((const float*)&v10)[j] + ((const float*)&v11)[j]);
        f2bf2(a * sc + sh, ohi[j], olo[j]);
    }
    short* dh = D + (((size_t)(bl * 2 + 0)) * 16384 + pix) * 16 + c4;
    short* dl = D + (((size_t)(bl * 2 + 1)) * 16384 + pix) * 16 + c4;
    *(int2*)dh = *(int2*)&ohi[0];
    *(int2*)dl = *(int2*)&olo[0];
}

// ---------------- MFMA 5x5 conv, 3-term hi/lo virtual chunks ----------------
// Block: 256 thr (4 waves), output tile 2 rows x 128 cols x OC.
// Wave w: row (w>>1), x-half (w&1)*64 -> 4 M-frags x OCF N-frags, K=32 = 2taps x 16ic.
// Virtual chunk vc in [0, 3*ICC): grp = vc/ICC selects (A,W) planes:
//   grp0 = (hi,hi), grp1 = (lo,hi), grp2 = (hi,lo); phys = vc % ICC.
template<int HW, int ICC, int OCF, int DIL>
__global__ __launch_bounds__(256) void convmf_kernel(
    const short* __restrict__ Din,   // [bl][plane][chunk][y][x][16]
    float* __restrict__ zout,        // [bl][y][x][OC] raw fp32
    const short* __restrict__ wgt, int wgt_off, int b0,
    float* __restrict__ stOut)
{
    constexpr int OC   = OCF * 16;
    constexpr int ROWS = 2 + 4 * DIL;
    constexpr int AW   = 136;
    constexpr int TG   = 7;
    __shared__ short As[ROWS * AW * 16];
    __shared__ short Ws[TG * OC * 32];
    __shared__ float s_stat[OC][2];

    int tid  = threadIdx.x;
    int lane = tid & 63;
    int w    = tid >> 6;
    int bl   = blockIdx.y;
    int xt   = (HW > 128) ? (blockIdx.x & 1) : 0;
    int rb   = (HW > 128) ? (blockIdx.x >> 1) : blockIdx.x;
    int y0   = rb * 2, x0 = xt * 128;
    int b    = b0 + bl;

    f32x4 acc[4][OCF];
    #pragma unroll
    for (int m = 0; m < 4; m++)
        #pragma unroll
        for (int n = 0; n < OCF; n++) acc[m][n] = (f32x4){0.f, 0.f, 0.f, 0.f};

    const size_t APL = (size_t)ICC * HW * HW * 16;   // A plane stride (shorts)
    const short* Db = Din + (size_t)bl * 2 * APL;
    const short* Wb = wgt + (size_t)b * WGT_STRIDE + wgt_off;

    int r_out = w >> 1;
    int xw = (w & 1) * 64;

    for (int vc = 0; vc < 3 * ICC; vc++) {
        int grp  = vc / ICC;
        int phys = vc - grp * ICC;
        const short* Ab = Db + (grp == 1 ? APL : 0);
        const short* Wp = Wb + (grp == 2 ? (size_t)WGT_PLANE : 0);

        __syncthreads();   // protect As from previous chunk's readers
        // ---- stage A chunk: ROWS x 136 x 16 bf16, zero OOB ----
        for (int i = tid; i < ROWS * AW * 2; i += 256) {
            int h  = i & 1;
            int hy = i >> 1;
            int y2 = hy / AW, x2 = hy - y2 * AW;
            int gy = y0 - 2 * DIL + y2;
            int gx = x0 - 2 * DIL + x2;
            int4 ld = {0, 0, 0, 0};
            if (gy >= 0 && gy < HW && gx >= 0 && gx < HW)
                ld = *(const int4*)(Ab + (((size_t)phys * HW + gy) * HW + gx) * 16 + h * 8);
            *(int4*)(As + (y2 * AW + x2) * 16 + h * 8) = ld;
        }
        for (int g = 0; g < 2; g++) {
            int p0 = g * TG;
            int np = (13 - p0 < TG) ? (13 - p0) : TG;
            __syncthreads();   // A staged / previous W group consumed
            // ---- stage W group: np pairs x OC x 4 quarters (16B each) ----
            for (int u = tid; u < np * OC * 4; u += 256) {
                int pp = u / (OC * 4);
                int rr = u - pp * (OC * 4);
                int oc = rr >> 2, q = rr & 3;
                int t  = (p0 + pp) * 2 + (q >> 1);   // tap 25 exists (zeros)
                int hh = q & 1;
                int4 wv = *(const int4*)(Wp + (((size_t)t * OC + oc) * (ICC * 16)) + phys * 16 + hh * 8);
                *(int4*)(Ws + ((size_t)pp * OC + oc) * 32 + (q ^ (oc & 3)) * 8) = wv;
            }
            __syncthreads();
            // ---- compute ----
            for (int pp = 0; pp < np; pp++) {
                int p = p0 + pp;
                int t = 2 * p + (lane >> 5);
                if (t == 25) t = 24;               // addr clamp; weights are zero
                int ky = t / 5, kx = t - 5 * ky;
                int h  = (lane >> 4) & 1;
                int yr = r_out + ky * DIL;
                int xb = xw + (lane & 15) + kx * DIL;
                const short* ap = As + ((size_t)(yr * AW + xb)) * 16 + h * 8;
                short8 a[4];
                #pragma unroll
                for (int m = 0; m < 4; m++) a[m] = *(const short8*)(ap + m * 256);
                short8 bf[OCF];
                int q = lane >> 4;
                #pragma unroll
                for (int n = 0; n < OCF; n++) {
                    int oc = n * 16 + (lane & 15);
                    bf[n] = *(const short8*)(Ws + ((size_t)pp * OC + oc) * 32 + (q ^ (oc & 3)) * 8);
                }
                #pragma unroll
                for (int m = 0; m < 4; m++)
                    #pragma unroll
                    for (int n = 0; n < OCF; n++)
                        acc[m][n] = __builtin_amdgcn_mfma_f32_16x16x32_bf16(
                            a[m], bf[n], acc[m][n], 0, 0, 0);
            }
        }
    }

    // ---- epilogue: stats + raw store ----
    for (int i = tid; i < OC * 2; i += 256) ((float*)s_stat)[i] = 0.f;
    __syncthreads();
    #pragma unroll
    for (int n = 0; n < OCF; n++) {
        float s = 0.f, q = 0.f;
        #pragma unroll
        for (int m = 0; m < 4; m++)
            #pragma unroll
            for (int r = 0; r < 4; r++) {
                float v = acc[m][n][r];
                s += v; q += v * v;
            }
        s += __shfl_xor(s, 16, 64); q += __shfl_xor(q, 16, 64);
        s += __shfl_xor(s, 32, 64); q += __shfl_xor(q, 32, 64);
        if (lane < 16) {
            atomicAdd(&s_stat[n * 16 + lane][0], s);
            atomicAdd(&s_stat[n * 16 + lane][1], q);
        }
    }
    int gy = y0 + r_out;
    float* zo = zout + ((size_t)bl * HW * HW + (size_t)gy * HW) * OC;
    #pragma unroll
    for (int m = 0; m < 4; m++) {
        int gx = x0 + xw + m * 16 + ((lane >> 4) << 2);
        #pragma unroll
        for (int n = 0; n < OCF; n++) {
            int oc = n * 16 + (lane & 15);
            #pragma unroll
            for (int r = 0; r < 4; r++)
                zo[(size_t)(gx + r) * OC + oc] = acc[m][n][r];
        }
    }
    __syncthreads();
    for (int i = tid; i < OC; i += 256) {
        atomicAdd(&stOut[((size_t)b * OC + i) * 2 + 0], s_stat[i][0]);
        atomicAdd(&stOut[((size_t)b * OC + i) * 2 + 1], s_stat[i][1]);
    }
}

// ---------------- 1x1 conv (layer 7), BN6-on-load, z6 [pix][64] -------------
__global__ __launch_bounds__(256) void conv1x1_kernel(
    const float* __restrict__ in, float* __restrict__ out,
    const float* __restrict__ wg, int b0,
    const float* __restrict__ stIn,
    const float* __restrict__ g, const float* __restrict__ be, float invN)
{
    __shared__ float s_w[512];
    __shared__ float s_scale[64], s_shift[64];
    int tid = threadIdx.x;
    int bl = blockIdx.y;
    int b  = b0 + bl;
    const float* wgb = wg + (size_t)b * WGF_STRIDE + 201600;
    for (int i = tid; i < 512; i += 256) s_w[i] = wgb[i];
    if (tid < 64) {
        float sum = stIn[(b * 64 + tid) * 2 + 0];
        float sq  = stIn[(b * 64 + tid) * 2 + 1];
        float m = sum * invN;
        float v = fmaxf(sq * invN - m * m, 0.f);
        float sc = g[tid] * rsqrtf(v + 1e-5f);
        s_scale[tid] = sc;
        s_shift[tid] = be[tid] - m * sc;
    }
    __syncthreads();

    int p = blockIdx.x * 256 + tid;   // 0..16383
    const float* ip = in + ((size_t)bl * 16384 + p) * 64;
    float acc[8] = {};
    #pragma unroll 4
    for (int icq = 0; icq < 16; icq++) {
        float4 v = *(const float4*)(ip + icq * 4);
        #pragma unroll
        for (int j = 0; j < 4; j++) {
            int ic = icq * 4 + j;
            float t = ((const float*)&v)[j] * s_scale[ic] + s_shift[ic];
            #pragma unroll
            for (int o = 0; o < 8; o++) acc[o] += s_w[o * 64 + ic] * t;
        }
    }
    float* op = out + ((size_t)bl * 16384 + p) * 8;
    *(float4*)(op)     = make_float4(acc[0], acc[1], acc[2], acc[3]);
    *(float4*)(op + 4) = make_float4(acc[4], acc[5], acc[6], acc[7]);
}

// ---------------- bilinear up x2 (align_corners) + softmax ------------------
// z7 layout [bl][pix128][8]
__global__ __launch_bounds__(256) void upsoft_kernel(
    const float* __restrict__ z7, float* __restrict__ outp, int b0)
{
    int idx = blockIdx.x * 256 + threadIdx.x;   // bl*65536 + y*256 + x
    int bl = idx >> 16;
    int b  = b0 + bl;
    int y = (idx >> 8) & 255;
    int x = idx & 255;
    const float kf = 127.f / 255.f;
    float sy = y * kf; int y0 = (int)sy; float wy = sy - y0; int y1 = min(y0 + 1, 127);
    float sx = x * kf; int x0 = (int)sx; float wx = sx - x0; int x1 = min(x0 + 1, 127);

    const float* base = z7 + (size_t)bl * 131072;
    float4 a00 = *(const float4*)(base + (y0 * 128 + x0) * 8);
    float4 b00 = *(const float4*)(base + (y0 * 128 + x0) * 8 + 4);
    float4 a01 = *(const float4*)(base + (y0 * 128 + x1) * 8);
    float4 b01 = *(const float4*)(base + (y0 * 128 + x1) * 8 + 4);
    float4 a10 = *(const float4*)(base + (y1 * 128 + x0) * 8);
    float4 b10 = *(const float4*)(base + (y1 * 128 + x0) * 8 + 4);
    float4 a11 = *(const float4*)(base + (y1 * 128 + x1) * 8);
    float4 b11 = *(const float4*)(base + (y1 * 128 + x1) * 8 + 4);

    float l[8];
    float mx = -1e30f;
    #pragma unroll
    for (int c = 0; c < 8; c++) {
        float v00 = (c < 4) ? ((const float*)&a00)[c] : ((const float*)&b00)[c - 4];
        float v01 = (c < 4) ? ((const float*)&a01)[c] : ((const float*)&b01)[c - 4];
        float v10 = (c < 4) ? ((const float*)&a10)[c] : ((const float*)&b10)[c - 4];
        float v11 = (c < 4) ? ((const float*)&a11)[c] : ((const float*)&b11)[c - 4];
        float ta = v00 * (1.f - wy) + v10 * wy;
        float tb = v01 * (1.f - wy) + v11 * wy;
        float v  = ta * (1.f - wx) + tb * wx;
        l[c] = v;
        mx = fmaxf(mx, v);
    }
    float s = 0.f;
    #pragma unroll
    for (int c = 0; c < 8; c++) { l[c] = expf(l[c] - mx); s += l[c]; }
    float inv = 1.f / s;
    #pragma unroll
    for (int c = 0; c < 8; c++)
        outp[((size_t)b * 8 + c) * 65536 + y * 256 + x] = l[c] * inv;
}

// ---------------------------------------------------------------------------
extern "C" void kernel_launch(void* const* d_in, const int* in_sizes, int n_in,
                              void* d_out, int out_size, void* d_ws, size_t ws_size,
                              hipStream_t stream)
{
    const float* x   = (const float*)d_in[0];
    const float* act = (const float*)d_in[1];
    const float* W[7]; const float* bv[7];
    for (int i = 0; i < 7; i++) { W[i] = (const float*)d_in[2 + 2*i]; bv[i] = (const float*)d_in[3 + 2*i]; }
    const float* g[7]; const float* be[7];
    for (int i = 0; i < 7; i++) { g[i] = (const float*)d_in[16 + 2*i]; be[i] = (const float*)d_in[17 + 2*i]; }
    float* out = (float*)d_out;

    // workspace (floats):
    //   wg  6,467,584 | wgt 6,815,744 (13,631,488 shorts, hi+lo) | st 14,848
    //   per sample: A 1,048,576 + B 1,048,576 + D 1,048,576 (2,097,152 shorts)
    int C = 8;
    while (C > 1) {
        size_t need = (13298176ull + 3ull * (size_t)C * 1048576ull) * 4ull;
        if (need <= ws_size) break;
        C >>= 1;
    }

    float* ws  = (float*)d_ws;
    float* wg  = ws;                                   // 6,467,584 floats
    short* wgt = (short*)(wg + 6467584);               // 13,631,488 shorts
    float* st  = ws + 13283328;                        // 14,848 floats
    float* A   = ws + 13298176;                        // C*1,048,576 floats (raw z)
    float* Bb  = A + (size_t)C * 1048576;              // C*1,048,576 floats (raw z)
    short* D   = (short*)(Bb + (size_t)C * 1048576);   // C*2,097,152 shorts (hi+lo)

    float* stx = st + 0;       // x  : 8 ch
    float* st1 = st + 512;     // z1 : 16
    float* st2 = st + 1536;    // z2 : 16
    float* st3 = st + 2560;    // z3 : 32
    float* st4 = st + 4608;    // z4 : 32
    float* st5 = st + 6656;    // z5 : 64
    float* st6 = st + 10752;   // z6 : 64

    hipMemsetAsync(st, 0, 14848 * sizeof(float), stream);

    wgen_kernel<<<790, 256, 0, stream>>>(act,
        W[0], bv[0], W[1], bv[1], W[2], bv[2], W[3], bv[3],
        W[4], bv[4], W[5], bv[5], W[6], bv[6], wg);
    wgt_kernel<<<26624, 256, 0, stream>>>(wg, wgt);
    stats_x_kernel<<<256, 256, 0, stream>>>(x, stx);

    const float iN256 = 1.f / 65536.f, iN128 = 1.f / 16384.f;

    for (int b0 = 0; b0 < NB; b0 += C) {
        // x -> D (BN0, pad ic to 16, hi/lo)
        prepass_x_kernel<<<C * 256, 256, 0, stream>>>(x, D, stx, g[0], be[0], b0);
        // conv1: D -> A (z1 raw [y][x][16]), stats st1
        convmf_kernel<256, 1, 1, 2><<<dim3(256, C), 256, 0, stream>>>(
            D, A, wgt, 0, b0, st1);
        // z1 -> D (BN1+relu)
        prepass_kernel<8, 16, true><<<C * 1024, 256, 0, stream>>>(
            A, D, st1, g[1], be[1], iN256, b0);
        // conv2: D -> B (z2 raw), stats st2
        convmf_kernel<256, 1, 1, 1><<<dim3(256, C), 256, 0, stream>>>(
            D, Bb, wgt, 6656, b0, st2);
        // z2 -> D (BN2 + pool)
        prepass_pool_kernel<<<C * 256, 256, 0, stream>>>(
            Bb, D, st2, g[2], be[2], b0);
        // conv3: D -> A (z3 raw [128][128][32]), stats st3
        convmf_kernel<128, 1, 2, 2><<<dim3(64, C), 256, 0, stream>>>(
            D, A, wgt, 13312, b0, st3);
        // z3 -> D (BN3+relu)
        prepass_kernel<7, 32, true><<<C * 512, 256, 0, stream>>>(
            A, D, st3, g[3], be[3], iN128, b0);
        // conv4: D -> B (z4 raw), stats st4
        convmf_kernel<128, 2, 2, 1><<<dim3(64, C), 256, 0, stream>>>(
            D, Bb, wgt, 26624, b0, st4);
        // z4 -> D (BN4)
        prepass_kernel<7, 32, false><<<C * 512, 256, 0, stream>>>(
            Bb, D, st4, g[4], be[4], iN128, b0);
        // conv5: D -> A (z5 raw [128][128][64]), stats st5
        convmf_kernel<128, 2, 4, 2><<<dim3(64, C), 256, 0, stream>>>(
            D, A, wgt, 53248, b0, st5);
        // z5 -> D (BN5+relu)
        prepass_kernel<7, 64, true><<<C * 1024, 256, 0, stream>>>(
            A, D, st5, g[5], be[5], iN128, b0);
        // conv6: D -> B (z6 raw), stats st6
        convmf_kernel<128, 4, 4, 1><<<dim3(64, C), 256, 0, stream>>>(
            D, Bb, wgt, 106496, b0, st6);
        // conv7: B(z6) -> A(z7 [pix][8]), BN6 on load
        conv1x1_kernel<<<dim3(64, C), 256, 0, stream>>>(
            Bb, A, wg, b0, st6, g[6], be[6], iN128);
        // upsample + softmax -> out
        upsoft_kernel<<<C * 256, 256, 0, stream>>>(A, out, b0);
    }
}